// Round 5
// baseline (239.784 us; speedup 1.0000x reference)
//
#include <hip/hip_runtime.h>
#include <hip/hip_bf16.h>
#include <math.h>

// B=2, L=2048, D=1024, H=16, Dh=64. M = B*L = 4096.
// prep:    w_qkv -> bf16 wqT [3072][1024], w_proj -> bf16 wpT [1024][1024], rope table [2048][32]
// gemm<0>: x(f32) @ wqT + RoPE -> q*0.125,k bf16 [bh][L][64]; v bf16 TRANSPOSED [bh][64][L]
// attn:    flash attention, swapped QK^T (lane-local softmax rows) -> ob bf16 [B,L,D]
// gemm<1>: ob(bf16) @ wpT -> f32 d_out

typedef __attribute__((ext_vector_type(8))) short bf16x8;
typedef __attribute__((ext_vector_type(4))) float f32x4;

__device__ __forceinline__ unsigned short f2bf(float f) {
    union { float f; unsigned int u; } v; v.f = f;
    unsigned int u = v.u;
    return (unsigned short)((u + 0x7FFFu + ((u >> 16) & 1u)) >> 16);
}

__device__ __forceinline__ unsigned short bfc(float f) {
    union { __hip_bfloat16 h; unsigned short u; } c;
    c.h = __float2bfloat16(f);
    return c.u;
}

__device__ __forceinline__ void gload_lds16(const unsigned short* g, unsigned short* l) {
    __builtin_amdgcn_global_load_lds(
        (const __attribute__((address_space(1))) void*)g,
        (__attribute__((address_space(3))) void*)l, 16, 0, 0);
}

// ---- prep: transpose f32 [1024][Ncols] -> bf16 [Ncols][1024] ----
__global__ __launch_bounds__(256) void prep_wT(const float* __restrict__ w,
                                               unsigned short* __restrict__ wT, int Ncols)
{
    __shared__ unsigned short t[32][34];
    int tid = threadIdx.x;
    int n0 = blockIdx.x * 32, k0 = blockIdx.y * 32;
    int r = tid >> 3, c4 = (tid & 7) * 4;
    float4 f = *(const float4*)(w + (size_t)(k0 + r) * Ncols + n0 + c4);
    t[c4 + 0][r] = f2bf(f.x);
    t[c4 + 1][r] = f2bf(f.y);
    t[c4 + 2][r] = f2bf(f.z);
    t[c4 + 3][r] = f2bf(f.w);
    __syncthreads();
    ushort4 o;
    o.x = t[r][c4]; o.y = t[r][c4 + 1]; o.z = t[r][c4 + 2]; o.w = t[r][c4 + 3];
    *(ushort4*)(wT + (size_t)(n0 + r) * 1024 + k0 + c4) = o;
}

// ---- prep: rope table tab[pos][d] = (cos, sin), pos<2048, d<32 ----
__global__ __launch_bounds__(256) void prep_rope(float2* __restrict__ tab)
{
    int i = blockIdx.x * 256 + threadIdx.x;        // 65536
    int pos = i >> 5, d = i & 31;
    float inv = expf(-0.28782313662f * (float)d);  // 10000^(-d/32)
    float ang = (float)pos * inv;
    float s, c;
    sincosf(ang, &s, &c);
    tab[i] = make_float2(c, s);
}

// ---- main GEMM, m97 structure: 128x128 tile, BK=64, global_load_lds B (and A in MODE1) ----
template<int MODE>
__global__ __launch_bounds__(256) void gemm_kernel(
    const void* __restrict__ Aptr, const unsigned short* __restrict__ BT,
    const float2* __restrict__ ropetab,
    unsigned short* __restrict__ qb, unsigned short* __restrict__ kb,
    unsigned short* __restrict__ vb, float* __restrict__ Cout, int N)
{
    const int K = 1024;
    __shared__ __align__(16) unsigned short As[128 * 64];
    __shared__ __align__(16) unsigned short Bs[128 * 64];
    int tid = threadIdx.x;
    int wid = tid >> 6, lane = tid & 63, lr = lane & 15, lg = lane >> 4;
    int wm = (wid >> 1) * 64, wn = (wid & 1) * 64;
    int row0 = blockIdx.y * 128, col0 = blockIdx.x * 128;

    f32x4 acc[4][4];
    #pragma unroll
    for (int m = 0; m < 4; ++m)
        #pragma unroll
        for (int n = 0; n < 4; ++n)
            #pragma unroll
            for (int i = 0; i < 4; ++i) acc[m][n][i] = 0.0f;

    for (int k0 = 0; k0 < K; k0 += 64) {
        #pragma unroll
        for (int i = 0; i < 4; ++i) {
            int cbase = (i * 4 + wid) * 64;
            int c = cbase + lane;
            int r = c >> 3, cc = (c & 7) * 8;
            gload_lds16(BT + (size_t)(col0 + r) * K + k0 + cc, Bs + cbase * 8);
        }
        if (MODE == 0) {
            const float* A = (const float*)Aptr;
            #pragma unroll
            for (int i = 0; i < 8; ++i) {
                int c = tid + i * 256;
                int r = c >> 4, cf = (c & 15) * 4;
                float4 f = *(const float4*)(A + (size_t)(row0 + r) * K + k0 + cf);
                ushort4 hh;
                hh.x = f2bf(f.x); hh.y = f2bf(f.y); hh.z = f2bf(f.z); hh.w = f2bf(f.w);
                *(ushort4*)(&As[r * 64 + cf]) = hh;
            }
        } else {
            const unsigned short* A = (const unsigned short*)Aptr;
            #pragma unroll
            for (int i = 0; i < 4; ++i) {
                int cbase = (i * 4 + wid) * 64;
                int c = cbase + lane;
                int r = c >> 3, cc = (c & 7) * 8;
                gload_lds16(A + (size_t)(row0 + r) * K + k0 + cc, As + cbase * 8);
            }
        }
        __syncthreads();
        #pragma unroll
        for (int kk = 0; kk < 2; ++kk) {
            bf16x8 af[4], bfr[4];
            #pragma unroll
            for (int m = 0; m < 4; ++m)
                af[m] = *(const bf16x8*)(&As[(wm + m * 16 + lr) * 64 + kk * 32 + lg * 8]);
            #pragma unroll
            for (int n = 0; n < 4; ++n)
                bfr[n] = *(const bf16x8*)(&Bs[(wn + n * 16 + lr) * 64 + kk * 32 + lg * 8]);
            #pragma unroll
            for (int m = 0; m < 4; ++m)
                #pragma unroll
                for (int n = 0; n < 4; ++n)
                    acc[m][n] = __builtin_amdgcn_mfma_f32_16x16x32_bf16(af[m], bfr[n], acc[m][n], 0, 0, 0);
        }
        __syncthreads();
    }

    if (MODE == 1) {
        #pragma unroll
        for (int m = 0; m < 4; ++m)
            #pragma unroll
            for (int reg = 0; reg < 4; ++reg) {
                int grow = row0 + wm + m * 16 + lg * 4 + reg;
                #pragma unroll
                for (int n = 0; n < 4; ++n)
                    Cout[(size_t)grow * N + col0 + wn + n * 16 + lr] = acc[m][n][reg];
            }
    } else {
        #pragma unroll
        for (int m = 0; m < 4; ++m)
            #pragma unroll
            for (int reg = 0; reg < 4; ++reg) {
                int grow = row0 + wm + m * 16 + lg * 4 + reg;
                int pos = grow & 2047;
                int bb = grow >> 11;
                #pragma unroll
                for (int n = 0; n < 4; ++n) {
                    int col = col0 + wn + n * 16 + lr;
                    int part = col >> 10;           // 0=q 1=k 2=v
                    int h = (col >> 6) & 15;
                    int d = col & 63;
                    float v0 = acc[m][n][reg];
                    if (part == 2) {
                        vb[((size_t)bb * 16 + h) * 131072 + (size_t)d * 2048 + pos] = f2bf(v0);
                    } else if (n < 2) {             // d<32, partner at n+2 (d+32) same lane
                        float v1 = acc[m][n + 2][reg];
                        float2 cs = ropetab[pos * 32 + d];
                        float qs = (part == 0) ? 0.125f : 1.0f;   // fold softmax scale into q
                        unsigned short* dst = (part == 0) ? qb : kb;
                        size_t base = (((size_t)bb * 16 + h) * 2048 + pos) * 64;
                        dst[base + d]      = f2bf((v0 * cs.x - v1 * cs.y) * qs);
                        dst[base + d + 32] = f2bf((v1 * cs.x + v0 * cs.y) * qs);
                    }
                }
            }
    }
}

// ---- flash attention v3: swapped QK^T, lane-local softmax rows ----
// 4 waves x 32 q-rows; K/V direct from global (L2-hot); P bounced via per-wave swizzled LDS.
#define PST 68   // Ps row stride (ushorts)
__global__ __launch_bounds__(256, 1) void attn_kernel(
    const unsigned short* __restrict__ qbuf, const unsigned short* __restrict__ kbuf,
    const unsigned short* __restrict__ vtbuf, const int* __restrict__ mask,
    unsigned short* __restrict__ obuf)
{
    __shared__ __align__(16) unsigned short Ps[4][32][PST];

    int qt = blockIdx.x, bh = blockIdx.y;
    int b = bh >> 4, h = bh & 15;
    int tid = threadIdx.x, wid = tid >> 6, lane = tid & 63, lr = lane & 15, lg = lane >> 4;
    int qrow0 = qt * 128 + wid * 32;
    const size_t bhbase = (size_t)bh * (2048 * 64);
    const unsigned short* vt = vtbuf + bhbase;   // [64][2048]
    const int* mptr = mask + b * 2048;
    unsigned short* psw = &Ps[wid][0][0];
    int sw3 = lr & 3;                             // row-dependent LDS swizzle key

    // Q fragments (B-operand): col q = r2*16+lr, k = kk*32+lg*8
    bf16x8 qf[2][2];
    #pragma unroll
    for (int r2 = 0; r2 < 2; ++r2)
        #pragma unroll
        for (int kk = 0; kk < 2; ++kk)
            qf[r2][kk] = *(const bf16x8*)(qbuf + bhbase + (size_t)(qrow0 + r2 * 16 + lr) * 64 + kk * 32 + lg * 8);

    f32x4 oacc[2][4];
    #pragma unroll
    for (int r2 = 0; r2 < 2; ++r2)
        #pragma unroll
        for (int n = 0; n < 4; ++n)
            #pragma unroll
            for (int i = 0; i < 4; ++i) oacc[r2][n][i] = 0.0f;
    float mrow[2] = {-INFINITY, -INFINITY};
    float lrow[2] = {0.f, 0.f};
    const f32x4 z4 = {0.f, 0.f, 0.f, 0.f};

    bf16x8 kfA[2][4], kfB[2][4];
    int mvA, mvB;
    #pragma unroll
    for (int kk = 0; kk < 2; ++kk)
        #pragma unroll
        for (int n = 0; n < 4; ++n)
            kfA[kk][n] = *(const bf16x8*)(kbuf + bhbase + (size_t)(n * 16 + lr) * 64 + kk * 32 + lg * 8);
    mvA = mptr[lane];

    auto tile = [&](int kv0, bf16x8 (&kf)[2][4], int mv, bf16x8 (&kfn)[2][4], int& mvn, bool pre) {
        // S^T = K Q^T : D[kv][q], lane: q = r2*16+lr, kv = n*16+lg*4+reg
        f32x4 sacc[2][4];
        #pragma unroll
        for (int r2 = 0; r2 < 2; ++r2)
            #pragma unroll
            for (int n = 0; n < 4; ++n) {
                sacc[r2][n] = __builtin_amdgcn_mfma_f32_16x16x32_bf16(kf[0][n], qf[r2][0], z4, 0, 0, 0);
                sacc[r2][n] = __builtin_amdgcn_mfma_f32_16x16x32_bf16(kf[1][n], qf[r2][1], sacc[r2][n], 0, 0, 0);
            }

        // prefetch V(t) and K(t+1)/mask(t+1)
        bf16x8 vf[2][4];
        #pragma unroll
        for (int kk = 0; kk < 2; ++kk)
            #pragma unroll
            for (int n = 0; n < 4; ++n)
                vf[kk][n] = *(const bf16x8*)(vt + (size_t)(n * 16 + lr) * 2048 + kv0 + kk * 32 + lg * 8);
        if (pre) {
            #pragma unroll
            for (int kk = 0; kk < 2; ++kk)
                #pragma unroll
                for (int n = 0; n < 4; ++n)
                    kfn[kk][n] = *(const bf16x8*)(kbuf + bhbase + (size_t)(kv0 + 64 + n * 16 + lr) * 64 + kk * 32 + lg * 8);
            mvn = mptr[kv0 + 64 + lane];
        }

        // mask (wave-uniform fast path when all live)
        unsigned long long bb = __ballot(mv != 0);
        if (bb != ~0ULL) {
            #pragma unroll
            for (int r2 = 0; r2 < 2; ++r2)
                #pragma unroll
                for (int n = 0; n < 4; ++n)
                    #pragma unroll
                    for (int reg = 0; reg < 4; ++reg) {
                        int kv = n * 16 + lg * 4 + reg;
                        if (!((bb >> kv) & 1)) sacc[r2][n][reg] = -1e30f;
                    }
        }

        // row max (16 in-lane + 2 shfl)
        float tmax[2];
        #pragma unroll
        for (int r2 = 0; r2 < 2; ++r2) {
            float t = sacc[r2][0][0];
            #pragma unroll
            for (int n = 0; n < 4; ++n)
                #pragma unroll
                for (int reg = 0; reg < 4; ++reg)
                    if (n | reg) t = fmaxf(t, sacc[r2][n][reg]);
            t = fmaxf(t, __shfl_xor(t, 16));
            t = fmaxf(t, __shfl_xor(t, 32));
            tmax[r2] = t;
        }

        // defer-max rescale (T13, THR=8)
        bool need = (tmax[0] > mrow[0] + 8.f) || (tmax[1] > mrow[1] + 8.f);
        if (__any(need)) {
            float sc[2];
            #pragma unroll
            for (int r2 = 0; r2 < 2; ++r2) {
                float mnew = fmaxf(mrow[r2], tmax[r2]);
                sc[r2] = (mrow[r2] == -INFINITY) ? 0.f : __expf(mrow[r2] - mnew);
                lrow[r2] *= sc[r2];
                mrow[r2] = mnew;
            }
            #pragma unroll
            for (int r2 = 0; r2 < 2; ++r2)
                #pragma unroll
                for (int reg = 0; reg < 4; ++reg) {
                    float scq = __shfl(sc[r2], lg * 4 + reg);
                    #pragma unroll
                    for (int n = 0; n < 4; ++n) oacc[r2][n][reg] *= scq;
                }
        }

        // P = exp(S - m), row-sum, pack to bf16, swizzled LDS store (b64)
        #pragma unroll
        for (int r2 = 0; r2 < 2; ++r2) {
            float ps = 0.f;
            unsigned short* prow = psw + (r2 * 16 + lr) * PST;
            #pragma unroll
            for (int n = 0; n < 4; ++n) {
                float p0 = __expf(sacc[r2][n][0] - mrow[r2]);
                float p1 = __expf(sacc[r2][n][1] - mrow[r2]);
                float p2 = __expf(sacc[r2][n][2] - mrow[r2]);
                float p3 = __expf(sacc[r2][n][3] - mrow[r2]);
                ps += (p0 + p1) + (p2 + p3);
                ushort4 w;
                w.x = bfc(p0); w.y = bfc(p1); w.z = bfc(p2); w.w = bfc(p3);
                int gb = 2 * n + (lg >> 1);
                int col = ((gb ^ sw3) << 3) + (lg & 1) * 4;
                *(ushort4*)(prow + col) = w;
            }
            ps += __shfl_xor(ps, 16);
            ps += __shfl_xor(ps, 32);
            lrow[r2] += ps;
        }

        // O += P V : A-frag rows q=lr, k=kv (swizzled read); B = V^T
        bf16x8 pf[2][2];
        #pragma unroll
        for (int r2 = 0; r2 < 2; ++r2)
            #pragma unroll
            for (int kk2 = 0; kk2 < 2; ++kk2) {
                int col = ((kk2 * 4 + lg) ^ sw3) << 3;
                pf[r2][kk2] = *(const bf16x8*)(psw + (r2 * 16 + lr) * PST + col);
            }
        #pragma unroll
        for (int kk2 = 0; kk2 < 2; ++kk2)
            #pragma unroll
            for (int r2 = 0; r2 < 2; ++r2)
                #pragma unroll
                for (int n = 0; n < 4; ++n)
                    oacc[r2][n] = __builtin_amdgcn_mfma_f32_16x16x32_bf16(pf[r2][kk2], vf[kk2][n], oacc[r2][n], 0, 0, 0);
    };

    #pragma unroll 1
    for (int it = 0; it < 16; ++it) {
        int kv0 = it * 128;
        tile(kv0, kfA, mvA, kfB, mvB, true);
        tile(kv0 + 64, kfB, mvB, kfA, mvA, kv0 + 128 < 2048);
    }

    // epilogue: O rows q = r2*16 + lg*4 + reg, cols d = n*16 + lr
    #pragma unroll
    for (int r2 = 0; r2 < 2; ++r2)
        #pragma unroll
        for (int reg = 0; reg < 4; ++reg) {
            float lq = __shfl(lrow[r2], lg * 4 + reg);
            float linv = 1.0f / lq;
            int qrow = qrow0 + r2 * 16 + lg * 4 + reg;
            #pragma unroll
            for (int n = 0; n < 4; ++n)
                obuf[((size_t)b * 2048 + qrow) * 1024 + h * 64 + n * 16 + lr] = bfc(oacc[r2][n][reg] * linv);
        }
}

extern "C" void kernel_launch(void* const* d_in, const int* in_sizes, int n_in,
                              void* d_out, int out_size, void* d_ws, size_t ws_size,
                              hipStream_t stream) {
    const float* x      = (const float*)d_in[0];
    const int* key_mask = (const int*)d_in[1];
    const float* w_qkv  = (const float*)d_in[2];
    const float* w_proj = (const float*)d_in[3];
    float* out = (float*)d_out;

    char* ws = (char*)d_ws;
    unsigned short* qb  = (unsigned short*)(ws);
    unsigned short* kb  = (unsigned short*)(ws + 8388608);
    unsigned short* vtb = (unsigned short*)(ws + 16777216);
    unsigned short* ob  = (unsigned short*)(ws + 25165824);
    unsigned short* wqT = (unsigned short*)(ws + 33554432);
    unsigned short* wpT = (unsigned short*)(ws + 39845888);
    float2*         tab = (float2*)(ws + 41943040);

    dim3 blk(256);
    prep_wT<<<dim3(96, 32), blk, 0, stream>>>(w_qkv, wqT, 3072);
    prep_wT<<<dim3(32, 32), blk, 0, stream>>>(w_proj, wpT, 1024);
    prep_rope<<<dim3(256), blk, 0, stream>>>(tab);
    gemm_kernel<0><<<dim3(24, 32), blk, 0, stream>>>(x, wqT, tab, qb, kb, vtb, nullptr, 3072);
    attn_kernel<<<dim3(16, 32), blk, 0, stream>>>(qb, kb, vtb, key_mask, ob);
    gemm_kernel<1><<<dim3(8, 32), blk, 0, stream>>>(ob, wpT, nullptr, nullptr, nullptr, nullptr, out, 1024);
}

// Round 6
// 236.635 us; speedup vs baseline: 1.0133x; 1.0133x over previous
//
#include <hip/hip_runtime.h>
#include <hip/hip_bf16.h>
#include <math.h>

// B=2, L=2048, D=1024, H=16, Dh=64. M = B*L = 4096.
// prep:    w_qkv -> bf16 wqT [3072][1024], w_proj -> bf16 wpT [1024][1024], rope table [2048][32]
// gemm<0>: x(f32) @ wqT + RoPE -> q*0.125,k bf16 [bh][L][64]; v bf16 TRANSPOSED [bh][64][L]
// attn:    flash attention, swapped QK^T, XCD-chunked blocks, 2-deep K/V prefetch
// gemm<1>: ob(bf16) @ wpT -> f32 d_out

typedef __attribute__((ext_vector_type(8))) short bf16x8;
typedef __attribute__((ext_vector_type(4))) float f32x4;

__device__ __forceinline__ unsigned short f2bf(float f) {
    union { float f; unsigned int u; } v; v.f = f;
    unsigned int u = v.u;
    return (unsigned short)((u + 0x7FFFu + ((u >> 16) & 1u)) >> 16);
}

__device__ __forceinline__ unsigned short bfc(float f) {
    union { __hip_bfloat16 h; unsigned short u; } c;
    c.h = __float2bfloat16(f);
    return c.u;
}

__device__ __forceinline__ void gload_lds16(const unsigned short* g, unsigned short* l) {
    __builtin_amdgcn_global_load_lds(
        (const __attribute__((address_space(1))) void*)g,
        (__attribute__((address_space(3))) void*)l, 16, 0, 0);
}

// ---- prep: transpose f32 [1024][Ncols] -> bf16 [Ncols][1024] ----
__global__ __launch_bounds__(256) void prep_wT(const float* __restrict__ w,
                                               unsigned short* __restrict__ wT, int Ncols)
{
    __shared__ unsigned short t[32][34];
    int tid = threadIdx.x;
    int n0 = blockIdx.x * 32, k0 = blockIdx.y * 32;
    int r = tid >> 3, c4 = (tid & 7) * 4;
    float4 f = *(const float4*)(w + (size_t)(k0 + r) * Ncols + n0 + c4);
    t[c4 + 0][r] = f2bf(f.x);
    t[c4 + 1][r] = f2bf(f.y);
    t[c4 + 2][r] = f2bf(f.z);
    t[c4 + 3][r] = f2bf(f.w);
    __syncthreads();
    ushort4 o;
    o.x = t[r][c4]; o.y = t[r][c4 + 1]; o.z = t[r][c4 + 2]; o.w = t[r][c4 + 3];
    *(ushort4*)(wT + (size_t)(n0 + r) * 1024 + k0 + c4) = o;
}

// ---- prep: rope table tab[pos][d] = (cos, sin), pos<2048, d<32 ----
__global__ __launch_bounds__(256) void prep_rope(float2* __restrict__ tab)
{
    int i = blockIdx.x * 256 + threadIdx.x;        // 65536
    int pos = i >> 5, d = i & 31;
    float inv = expf(-0.28782313662f * (float)d);  // 10000^(-d/32)
    float ang = (float)pos * inv;
    float s, c;
    sincosf(ang, &s, &c);
    tab[i] = make_float2(c, s);
}

// ---- main GEMM, m97 structure: 128x128 tile, BK=64, global_load_lds B (and A in MODE1) ----
template<int MODE>
__global__ __launch_bounds__(256) void gemm_kernel(
    const void* __restrict__ Aptr, const unsigned short* __restrict__ BT,
    const float2* __restrict__ ropetab,
    unsigned short* __restrict__ qb, unsigned short* __restrict__ kb,
    unsigned short* __restrict__ vb, float* __restrict__ Cout, int N)
{
    const int K = 1024;
    __shared__ __align__(16) unsigned short As[128 * 64];
    __shared__ __align__(16) unsigned short Bs[128 * 64];
    int tid = threadIdx.x;
    int wid = tid >> 6, lane = tid & 63, lr = lane & 15, lg = lane >> 4;
    int wm = (wid >> 1) * 64, wn = (wid & 1) * 64;
    int row0 = blockIdx.y * 128, col0 = blockIdx.x * 128;

    f32x4 acc[4][4];
    #pragma unroll
    for (int m = 0; m < 4; ++m)
        #pragma unroll
        for (int n = 0; n < 4; ++n)
            #pragma unroll
            for (int i = 0; i < 4; ++i) acc[m][n][i] = 0.0f;

    for (int k0 = 0; k0 < K; k0 += 64) {
        #pragma unroll
        for (int i = 0; i < 4; ++i) {
            int cbase = (i * 4 + wid) * 64;
            int c = cbase + lane;
            int r = c >> 3, cc = (c & 7) * 8;
            gload_lds16(BT + (size_t)(col0 + r) * K + k0 + cc, Bs + cbase * 8);
        }
        if (MODE == 0) {
            const float* A = (const float*)Aptr;
            #pragma unroll
            for (int i = 0; i < 8; ++i) {
                int c = tid + i * 256;
                int r = c >> 4, cf = (c & 15) * 4;
                float4 f = *(const float4*)(A + (size_t)(row0 + r) * K + k0 + cf);
                ushort4 hh;
                hh.x = f2bf(f.x); hh.y = f2bf(f.y); hh.z = f2bf(f.z); hh.w = f2bf(f.w);
                *(ushort4*)(&As[r * 64 + cf]) = hh;
            }
        } else {
            const unsigned short* A = (const unsigned short*)Aptr;
            #pragma unroll
            for (int i = 0; i < 4; ++i) {
                int cbase = (i * 4 + wid) * 64;
                int c = cbase + lane;
                int r = c >> 3, cc = (c & 7) * 8;
                gload_lds16(A + (size_t)(row0 + r) * K + k0 + cc, As + cbase * 8);
            }
        }
        __syncthreads();
        #pragma unroll
        for (int kk = 0; kk < 2; ++kk) {
            bf16x8 af[4], bfr[4];
            #pragma unroll
            for (int m = 0; m < 4; ++m)
                af[m] = *(const bf16x8*)(&As[(wm + m * 16 + lr) * 64 + kk * 32 + lg * 8]);
            #pragma unroll
            for (int n = 0; n < 4; ++n)
                bfr[n] = *(const bf16x8*)(&Bs[(wn + n * 16 + lr) * 64 + kk * 32 + lg * 8]);
            #pragma unroll
            for (int m = 0; m < 4; ++m)
                #pragma unroll
                for (int n = 0; n < 4; ++n)
                    acc[m][n] = __builtin_amdgcn_mfma_f32_16x16x32_bf16(af[m], bfr[n], acc[m][n], 0, 0, 0);
        }
        __syncthreads();
    }

    if (MODE == 1) {
        #pragma unroll
        for (int m = 0; m < 4; ++m)
            #pragma unroll
            for (int reg = 0; reg < 4; ++reg) {
                int grow = row0 + wm + m * 16 + lg * 4 + reg;
                #pragma unroll
                for (int n = 0; n < 4; ++n)
                    Cout[(size_t)grow * N + col0 + wn + n * 16 + lr] = acc[m][n][reg];
            }
    } else {
        #pragma unroll
        for (int m = 0; m < 4; ++m)
            #pragma unroll
            for (int reg = 0; reg < 4; ++reg) {
                int grow = row0 + wm + m * 16 + lg * 4 + reg;
                int pos = grow & 2047;
                int bb = grow >> 11;
                #pragma unroll
                for (int n = 0; n < 4; ++n) {
                    int col = col0 + wn + n * 16 + lr;
                    int part = col >> 10;           // 0=q 1=k 2=v
                    int h = (col >> 6) & 15;
                    int d = col & 63;
                    float v0 = acc[m][n][reg];
                    if (part == 2) {
                        vb[((size_t)bb * 16 + h) * 131072 + (size_t)d * 2048 + pos] = f2bf(v0);
                    } else if (n < 2) {             // d<32, partner at n+2 (d+32) same lane
                        float v1 = acc[m][n + 2][reg];
                        float2 cs = ropetab[pos * 32 + d];
                        float qs = (part == 0) ? 0.125f : 1.0f;   // fold softmax scale into q
                        unsigned short* dst = (part == 0) ? qb : kb;
                        size_t base = (((size_t)bb * 16 + h) * 2048 + pos) * 64;
                        dst[base + d]      = f2bf((v0 * cs.x - v1 * cs.y) * qs);
                        dst[base + d + 32] = f2bf((v1 * cs.x + v0 * cs.y) * qs);
                    }
                }
            }
    }
}

// ---- flash attention v4: swapped QK^T + XCD-chunked blocks + 2-deep K/V prefetch ----
#define PST 68   // Ps row stride (ushorts)
__global__ __launch_bounds__(256, 1) void attn_kernel(
    const unsigned short* __restrict__ qbuf, const unsigned short* __restrict__ kbuf,
    const unsigned short* __restrict__ vtbuf, const int* __restrict__ mask,
    unsigned short* __restrict__ obuf)
{
    __shared__ __align__(16) unsigned short Ps[4][32][PST];

    // XCD-chunked remap: 512 blocks, 8 XCDs -> each XCD gets 64 consecutive work ids
    // (= 4 bh's, whose K/V [2MB] fit its 4MB L2).
    int flat = blockIdx.x;
    int w = ((flat & 7) << 6) + (flat >> 3);
    int bh = w >> 4, qt = w & 15;
    int b = bh >> 4, h = bh & 15;
    int tid = threadIdx.x, wid = tid >> 6, lane = tid & 63, lr = lane & 15, lg = lane >> 4;
    int qrow0 = qt * 128 + wid * 32;
    const size_t bhbase = (size_t)bh * (2048 * 64);
    const unsigned short* vt = vtbuf + bhbase;   // [64][2048]
    const int* mptr = mask + b * 2048;
    unsigned short* psw = &Ps[wid][0][0];
    int sw3 = lr & 3;                             // row-dependent LDS swizzle key

    // Q fragments (B-operand): col q = r2*16+lr, k = kk*32+lg*8
    bf16x8 qf[2][2];
    #pragma unroll
    for (int r2 = 0; r2 < 2; ++r2)
        #pragma unroll
        for (int kk = 0; kk < 2; ++kk)
            qf[r2][kk] = *(const bf16x8*)(qbuf + bhbase + (size_t)(qrow0 + r2 * 16 + lr) * 64 + kk * 32 + lg * 8);

    f32x4 oacc[2][4];
    #pragma unroll
    for (int r2 = 0; r2 < 2; ++r2)
        #pragma unroll
        for (int n = 0; n < 4; ++n)
            #pragma unroll
            for (int i = 0; i < 4; ++i) oacc[r2][n][i] = 0.0f;
    float mrow[2] = {-INFINITY, -INFINITY};
    float lrow[2] = {0.f, 0.f};
    const f32x4 z4 = {0.f, 0.f, 0.f, 0.f};

    bf16x8 kfA[2][4], kfB[2][4], vfA[2][4], vfB[2][4];
    int mvA, mvB;
    #pragma unroll
    for (int kk = 0; kk < 2; ++kk)
        #pragma unroll
        for (int n = 0; n < 4; ++n) {
            kfA[kk][n] = *(const bf16x8*)(kbuf + bhbase + (size_t)(n * 16 + lr) * 64 + kk * 32 + lg * 8);
            vfA[kk][n] = *(const bf16x8*)(vt + (size_t)(n * 16 + lr) * 2048 + kk * 32 + lg * 8);
        }
    mvA = mptr[lane];

    auto tile = [&](int kv0, bf16x8 (&kf)[2][4], bf16x8 (&vf)[2][4], int mv,
                    bf16x8 (&kfn)[2][4], bf16x8 (&vfn)[2][4], int& mvn, bool pre) {
        // S^T = K Q^T : D[kv][q], lane: q = r2*16+lr, kv = n*16+lg*4+reg
        f32x4 sacc[2][4];
        #pragma unroll
        for (int r2 = 0; r2 < 2; ++r2)
            #pragma unroll
            for (int n = 0; n < 4; ++n) {
                sacc[r2][n] = __builtin_amdgcn_mfma_f32_16x16x32_bf16(kf[0][n], qf[r2][0], z4, 0, 0, 0);
                sacc[r2][n] = __builtin_amdgcn_mfma_f32_16x16x32_bf16(kf[1][n], qf[r2][1], sacc[r2][n], 0, 0, 0);
            }

        // prefetch K(t+1), V(t+1), mask(t+1) — full tile of latency cover
        if (pre) {
            #pragma unroll
            for (int kk = 0; kk < 2; ++kk)
                #pragma unroll
                for (int n = 0; n < 4; ++n) {
                    kfn[kk][n] = *(const bf16x8*)(kbuf + bhbase + (size_t)(kv0 + 64 + n * 16 + lr) * 64 + kk * 32 + lg * 8);
                    vfn[kk][n] = *(const bf16x8*)(vt + (size_t)(n * 16 + lr) * 2048 + kv0 + 64 + kk * 32 + lg * 8);
                }
            mvn = mptr[kv0 + 64 + lane];
        }

        // mask (wave-uniform fast path when all live)
        unsigned long long bb = __ballot(mv != 0);
        if (bb != ~0ULL) {
            #pragma unroll
            for (int r2 = 0; r2 < 2; ++r2)
                #pragma unroll
                for (int n = 0; n < 4; ++n)
                    #pragma unroll
                    for (int reg = 0; reg < 4; ++reg) {
                        int kv = n * 16 + lg * 4 + reg;
                        if (!((bb >> kv) & 1)) sacc[r2][n][reg] = -1e30f;
                    }
        }

        // row max: balanced tree (v_max3-friendly) + 2 shfl
        float tmax[2];
        #pragma unroll
        for (int r2 = 0; r2 < 2; ++r2) {
            float a0 = fmaxf(fmaxf(sacc[r2][0][0], sacc[r2][0][1]), fmaxf(sacc[r2][0][2], sacc[r2][0][3]));
            float a1 = fmaxf(fmaxf(sacc[r2][1][0], sacc[r2][1][1]), fmaxf(sacc[r2][1][2], sacc[r2][1][3]));
            float a2 = fmaxf(fmaxf(sacc[r2][2][0], sacc[r2][2][1]), fmaxf(sacc[r2][2][2], sacc[r2][2][3]));
            float a3 = fmaxf(fmaxf(sacc[r2][3][0], sacc[r2][3][1]), fmaxf(sacc[r2][3][2], sacc[r2][3][3]));
            float t = fmaxf(fmaxf(a0, a1), fmaxf(a2, a3));
            t = fmaxf(t, __shfl_xor(t, 16));
            t = fmaxf(t, __shfl_xor(t, 32));
            tmax[r2] = t;
        }

        // defer-max rescale (T13, THR=8)
        bool need = (tmax[0] > mrow[0] + 8.f) || (tmax[1] > mrow[1] + 8.f);
        if (__any(need)) {
            float sc[2];
            #pragma unroll
            for (int r2 = 0; r2 < 2; ++r2) {
                float mnew = fmaxf(mrow[r2], tmax[r2]);
                sc[r2] = (mrow[r2] == -INFINITY) ? 0.f : __expf(mrow[r2] - mnew);
                lrow[r2] *= sc[r2];
                mrow[r2] = mnew;
            }
            #pragma unroll
            for (int r2 = 0; r2 < 2; ++r2)
                #pragma unroll
                for (int reg = 0; reg < 4; ++reg) {
                    float scq = __shfl(sc[r2], lg * 4 + reg);
                    #pragma unroll
                    for (int n = 0; n < 4; ++n) oacc[r2][n][reg] *= scq;
                }
        }

        // P = exp(S - m), row-sum, pack to bf16, swizzled LDS store (b64)
        #pragma unroll
        for (int r2 = 0; r2 < 2; ++r2) {
            float ps = 0.f;
            unsigned short* prow = psw + (r2 * 16 + lr) * PST;
            #pragma unroll
            for (int n = 0; n < 4; ++n) {
                float p0 = __expf(sacc[r2][n][0] - mrow[r2]);
                float p1 = __expf(sacc[r2][n][1] - mrow[r2]);
                float p2 = __expf(sacc[r2][n][2] - mrow[r2]);
                float p3 = __expf(sacc[r2][n][3] - mrow[r2]);
                ps += (p0 + p1) + (p2 + p3);
                ushort4 wv;
                wv.x = bfc(p0); wv.y = bfc(p1); wv.z = bfc(p2); wv.w = bfc(p3);
                int gb = 2 * n + (lg >> 1);
                int col = ((gb ^ sw3) << 3) + (lg & 1) * 4;
                *(ushort4*)(prow + col) = wv;
            }
            ps += __shfl_xor(ps, 16);
            ps += __shfl_xor(ps, 32);
            lrow[r2] += ps;
        }

        // O += P V : A-frag rows q=lr, k=kv (swizzled read); B = V^T
        bf16x8 pf[2][2];
        #pragma unroll
        for (int r2 = 0; r2 < 2; ++r2)
            #pragma unroll
            for (int kk2 = 0; kk2 < 2; ++kk2) {
                int col = ((kk2 * 4 + lg) ^ sw3) << 3;
                pf[r2][kk2] = *(const bf16x8*)(psw + (r2 * 16 + lr) * PST + col);
            }
        #pragma unroll
        for (int kk2 = 0; kk2 < 2; ++kk2)
            #pragma unroll
            for (int r2 = 0; r2 < 2; ++r2)
                #pragma unroll
                for (int n = 0; n < 4; ++n)
                    oacc[r2][n] = __builtin_amdgcn_mfma_f32_16x16x32_bf16(pf[r2][kk2], vf[kk2][n], oacc[r2][n], 0, 0, 0);
    };

    #pragma unroll 1
    for (int it = 0; it < 16; ++it) {
        int kv0 = it * 128;
        tile(kv0, kfA, vfA, mvA, kfB, vfB, mvB, true);
        tile(kv0 + 64, kfB, vfB, mvB, kfA, vfA, mvA, kv0 + 128 < 2048);
    }

    // epilogue: O rows q = r2*16 + lg*4 + reg, cols d = n*16 + lr
    #pragma unroll
    for (int r2 = 0; r2 < 2; ++r2)
        #pragma unroll
        for (int reg = 0; reg < 4; ++reg) {
            float lq = __shfl(lrow[r2], lg * 4 + reg);
            float linv = 1.0f / lq;
            int qrow = qrow0 + r2 * 16 + lg * 4 + reg;
            #pragma unroll
            for (int n = 0; n < 4; ++n)
                obuf[((size_t)b * 2048 + qrow) * 1024 + h * 64 + n * 16 + lr] = bfc(oacc[r2][n][reg] * linv);
        }
}

extern "C" void kernel_launch(void* const* d_in, const int* in_sizes, int n_in,
                              void* d_out, int out_size, void* d_ws, size_t ws_size,
                              hipStream_t stream) {
    const float* x      = (const float*)d_in[0];
    const int* key_mask = (const int*)d_in[1];
    const float* w_qkv  = (const float*)d_in[2];
    const float* w_proj = (const float*)d_in[3];
    float* out = (float*)d_out;

    char* ws = (char*)d_ws;
    unsigned short* qb  = (unsigned short*)(ws);
    unsigned short* kb  = (unsigned short*)(ws + 8388608);
    unsigned short* vtb = (unsigned short*)(ws + 16777216);
    unsigned short* ob  = (unsigned short*)(ws + 25165824);
    unsigned short* wqT = (unsigned short*)(ws + 33554432);
    unsigned short* wpT = (unsigned short*)(ws + 39845888);
    float2*         tab = (float2*)(ws + 41943040);

    dim3 blk(256);
    prep_wT<<<dim3(96, 32), blk, 0, stream>>>(w_qkv, wqT, 3072);
    prep_wT<<<dim3(32, 32), blk, 0, stream>>>(w_proj, wpT, 1024);
    prep_rope<<<dim3(256), blk, 0, stream>>>(tab);
    gemm_kernel<0><<<dim3(24, 32), blk, 0, stream>>>(x, wqT, tab, qb, kb, vtb, nullptr, 3072);
    attn_kernel<<<dim3(512), blk, 0, stream>>>(qb, kb, vtb, key_mask, ob);
    gemm_kernel<1><<<dim3(8, 32), blk, 0, stream>>>(ob, wpT, nullptr, nullptr, nullptr, nullptr, out, 1024);
}

// Round 7
// 193.269 us; speedup vs baseline: 1.2407x; 1.2244x over previous
//
#include <hip/hip_runtime.h>
#include <hip/hip_bf16.h>
#include <math.h>

// B=2, L=2048, D=1024, H=16, Dh=64. M = B*L = 4096.
// prep:    w_qkv -> bf16 wqT [3072][1024], w_proj -> bf16 wpT [1024][1024], rope table [2048][32]
// gemm<0>: x(f32) @ wqT + RoPE -> q*0.125 (natural), k (XOR-swizzled rows), v^T (XOR-swizzled row-tiles)
// attn:    flash attention, swapped QK^T, LDS-staged shared K/V (dbuf, global_load_lds), 8 waves/block
// gemm<1>: ob(bf16) @ wpT -> f32 d_out

typedef __attribute__((ext_vector_type(8))) short bf16x8;
typedef __attribute__((ext_vector_type(4))) float f32x4;

__device__ __forceinline__ unsigned short f2bf(float f) {
    union { float f; unsigned int u; } v; v.f = f;
    unsigned int u = v.u;
    return (unsigned short)((u + 0x7FFFu + ((u >> 16) & 1u)) >> 16);
}

__device__ __forceinline__ unsigned short bfc(float f) {
    union { __hip_bfloat16 h; unsigned short u; } c;
    c.h = __float2bfloat16(f);
    return c.u;
}

__device__ __forceinline__ void gload_lds16(const unsigned short* g, unsigned short* l) {
    __builtin_amdgcn_global_load_lds(
        (const __attribute__((address_space(1))) void*)g,
        (__attribute__((address_space(3))) void*)l, 16, 0, 0);
}

// ---- prep: transpose f32 [1024][Ncols] -> bf16 [Ncols][1024] ----
__global__ __launch_bounds__(256) void prep_wT(const float* __restrict__ w,
                                               unsigned short* __restrict__ wT, int Ncols)
{
    __shared__ unsigned short t[32][34];
    int tid = threadIdx.x;
    int n0 = blockIdx.x * 32, k0 = blockIdx.y * 32;
    int r = tid >> 3, c4 = (tid & 7) * 4;
    float4 f = *(const float4*)(w + (size_t)(k0 + r) * Ncols + n0 + c4);
    t[c4 + 0][r] = f2bf(f.x);
    t[c4 + 1][r] = f2bf(f.y);
    t[c4 + 2][r] = f2bf(f.z);
    t[c4 + 3][r] = f2bf(f.w);
    __syncthreads();
    ushort4 o;
    o.x = t[r][c4]; o.y = t[r][c4 + 1]; o.z = t[r][c4 + 2]; o.w = t[r][c4 + 3];
    *(ushort4*)(wT + (size_t)(n0 + r) * 1024 + k0 + c4) = o;
}

// ---- prep: rope table tab[pos][d] = (cos, sin), pos<2048, d<32 ----
__global__ __launch_bounds__(256) void prep_rope(float2* __restrict__ tab)
{
    int i = blockIdx.x * 256 + threadIdx.x;        // 65536
    int pos = i >> 5, d = i & 31;
    float inv = expf(-0.28782313662f * (float)d);  // 10000^(-d/32)
    float ang = (float)pos * inv;
    float s, c;
    sincosf(ang, &s, &c);
    tab[i] = make_float2(c, s);
}

// ---- main GEMM, m97 structure: 128x128 tile, BK=64, global_load_lds B (and A in MODE1) ----
template<int MODE>
__global__ __launch_bounds__(256) void gemm_kernel(
    const void* __restrict__ Aptr, const unsigned short* __restrict__ BT,
    const float2* __restrict__ ropetab,
    unsigned short* __restrict__ qb, unsigned short* __restrict__ kb,
    unsigned short* __restrict__ vb, float* __restrict__ Cout, int N)
{
    const int K = 1024;
    __shared__ __align__(16) unsigned short As[128 * 64];
    __shared__ __align__(16) unsigned short Bs[128 * 64];
    int tid = threadIdx.x;
    int wid = tid >> 6, lane = tid & 63, lr = lane & 15, lg = lane >> 4;
    int wm = (wid >> 1) * 64, wn = (wid & 1) * 64;
    int row0 = blockIdx.y * 128, col0 = blockIdx.x * 128;

    f32x4 acc[4][4];
    #pragma unroll
    for (int m = 0; m < 4; ++m)
        #pragma unroll
        for (int n = 0; n < 4; ++n)
            #pragma unroll
            for (int i = 0; i < 4; ++i) acc[m][n][i] = 0.0f;

    for (int k0 = 0; k0 < K; k0 += 64) {
        #pragma unroll
        for (int i = 0; i < 4; ++i) {
            int cbase = (i * 4 + wid) * 64;
            int c = cbase + lane;
            int r = c >> 3, cc = (c & 7) * 8;
            gload_lds16(BT + (size_t)(col0 + r) * K + k0 + cc, Bs + cbase * 8);
        }
        if (MODE == 0) {
            const float* A = (const float*)Aptr;
            #pragma unroll
            for (int i = 0; i < 8; ++i) {
                int c = tid + i * 256;
                int r = c >> 4, cf = (c & 15) * 4;
                float4 f = *(const float4*)(A + (size_t)(row0 + r) * K + k0 + cf);
                ushort4 hh;
                hh.x = f2bf(f.x); hh.y = f2bf(f.y); hh.z = f2bf(f.z); hh.w = f2bf(f.w);
                *(ushort4*)(&As[r * 64 + cf]) = hh;
            }
        } else {
            const unsigned short* A = (const unsigned short*)Aptr;
            #pragma unroll
            for (int i = 0; i < 4; ++i) {
                int cbase = (i * 4 + wid) * 64;
                int c = cbase + lane;
                int r = c >> 3, cc = (c & 7) * 8;
                gload_lds16(A + (size_t)(row0 + r) * K + k0 + cc, As + cbase * 8);
            }
        }
        __syncthreads();
        #pragma unroll
        for (int kk = 0; kk < 2; ++kk) {
            bf16x8 af[4], bfr[4];
            #pragma unroll
            for (int m = 0; m < 4; ++m)
                af[m] = *(const bf16x8*)(&As[(wm + m * 16 + lr) * 64 + kk * 32 + lg * 8]);
            #pragma unroll
            for (int n = 0; n < 4; ++n)
                bfr[n] = *(const bf16x8*)(&Bs[(wn + n * 16 + lr) * 64 + kk * 32 + lg * 8]);
            #pragma unroll
            for (int m = 0; m < 4; ++m)
                #pragma unroll
                for (int n = 0; n < 4; ++n)
                    acc[m][n] = __builtin_amdgcn_mfma_f32_16x16x32_bf16(af[m], bfr[n], acc[m][n], 0, 0, 0);
        }
        __syncthreads();
    }

    if (MODE == 1) {
        #pragma unroll
        for (int m = 0; m < 4; ++m)
            #pragma unroll
            for (int reg = 0; reg < 4; ++reg) {
                int grow = row0 + wm + m * 16 + lg * 4 + reg;
                #pragma unroll
                for (int n = 0; n < 4; ++n)
                    Cout[(size_t)grow * N + col0 + wn + n * 16 + lr] = acc[m][n][reg];
            }
    } else {
        #pragma unroll
        for (int m = 0; m < 4; ++m)
            #pragma unroll
            for (int reg = 0; reg < 4; ++reg) {
                int grow = row0 + wm + m * 16 + lg * 4 + reg;
                int pos = grow & 2047;
                int bb = grow >> 11;
                #pragma unroll
                for (int n = 0; n < 4; ++n) {
                    int col = col0 + wn + n * 16 + lr;
                    int part = col >> 10;           // 0=q 1=k 2=v
                    int h = (col >> 6) & 15;
                    int d = col & 63;
                    float v0 = acc[m][n][reg];
                    if (part == 2) {
                        // v^T with XOR-swizzled 64-wide row tiles: elem (d, pos)
                        int posl = (pos & 63) ^ ((d & 7) << 3);
                        vb[((size_t)bb * 16 + h) * 131072 + (size_t)d * 2048 + (pos & ~63) + posl] = f2bf(v0);
                    } else if (n < 2) {             // d<32, partner at n+2 (d+32) same lane
                        float v1 = acc[m][n + 2][reg];
                        float2 cs = ropetab[pos * 32 + d];
                        size_t base = (((size_t)bb * 16 + h) * 2048 + pos) * 64;
                        float e0 = v0 * cs.x - v1 * cs.y;
                        float e1 = v1 * cs.x + v0 * cs.y;
                        if (part == 0) {            // q natural, fold softmax scale
                            qb[base + d]      = f2bf(e0 * 0.125f);
                            qb[base + d + 32] = f2bf(e1 * 0.125f);
                        } else {                    // k row-swizzled
                            int sw = (pos & 7) << 3;
                            kb[base + (d ^ sw)]        = f2bf(e0);
                            kb[base + ((d + 32) ^ sw)] = f2bf(e1);
                        }
                    }
                }
            }
    }
}

// ---- flash attention v5: 8 waves x 16 q-rows; dbuf LDS K/V via global_load_lds ----
#define PST 68   // Ps row stride (ushorts)
__global__ __launch_bounds__(512, 4) void attn_kernel(
    const unsigned short* __restrict__ qbuf, const unsigned short* __restrict__ kbuf,
    const unsigned short* __restrict__ vtbuf, const int* __restrict__ mask,
    unsigned short* __restrict__ obuf)
{
    __shared__ __align__(16) unsigned short Ks[2][4096];   // [kvl][d^swz] 64x64
    __shared__ __align__(16) unsigned short Vs[2][4096];   // [d][kvl^swz] 64x64
    __shared__ __align__(16) unsigned short Ps[8][16][PST];

    // XCD-chunked remap: 512 blocks, 8 XCDs, 64 consecutive w per XCD (4 bh -> 2MB K/V in L2)
    int flat = blockIdx.x;
    int w = ((flat & 7) << 6) + (flat >> 3);
    int bh = w >> 4, qt = w & 15;
    int b = bh >> 4, h = bh & 15;
    int tid = threadIdx.x, wid = tid >> 6, lane = tid & 63, lr = lane & 15, lg = lane >> 4;
    int qrow0 = qt * 128 + wid * 16;
    const size_t bhbase = (size_t)bh * (2048 * 64);
    const unsigned short* kB = kbuf + bhbase;
    const unsigned short* vt = vtbuf + bhbase;   // [64][2048] swizzled row-tiles
    const int* mptr = mask + b * 2048;
    unsigned short* prow = &Ps[wid][lr][0];
    int sw3 = lr & 3;
    int swk = (lr & 7) << 3;                      // K/V LDS read swizzle (elements)

    // Q fragments (B-operand): col q = lr, k = kk*32+lg*8
    bf16x8 qf[2];
    #pragma unroll
    for (int kk = 0; kk < 2; ++kk)
        qf[kk] = *(const bf16x8*)(qbuf + bhbase + (size_t)(qrow0 + lr) * 64 + kk * 32 + lg * 8);

    f32x4 oacc[4];
    #pragma unroll
    for (int n = 0; n < 4; ++n)
        #pragma unroll
        for (int i = 0; i < 4; ++i) oacc[n][i] = 0.0f;
    float mrow = -INFINITY, lrow = 0.f;
    const f32x4 z4 = {0.f, 0.f, 0.f, 0.f};

    // staging: per thread 1x16B of K + 1x16B of V
    auto stage = [&](int t, int buf) {
        gload_lds16(kB + (size_t)t * 4096 + tid * 8, &Ks[buf][wid * 512]);
        gload_lds16(vt + (size_t)(tid >> 3) * 2048 + t * 64 + (tid & 7) * 8, &Vs[buf][wid * 512]);
    };

    stage(0, 0);
    #pragma unroll 1
    for (int t = 0; t < 32; ++t) {
        int cur = t & 1;
        __syncthreads();                  // drains staging of buf[cur]
        if (t < 31) stage(t + 1, cur ^ 1);
        const unsigned short* Kc = Ks[cur];
        const unsigned short* Vc = Vs[cur];
        int mv = mptr[t * 64 + lane];

        // K fragments (A-operand): row kv = n*16+lr, k(d) = kk*32+lg*8 (^swz)
        bf16x8 kf[2][4];
        #pragma unroll
        for (int kk = 0; kk < 2; ++kk)
            #pragma unroll
            for (int n = 0; n < 4; ++n)
                kf[kk][n] = *(const bf16x8*)(Kc + (n * 16 + lr) * 64 + ((kk * 32 + lg * 8) ^ swk));

        // S^T = K Q^T : D[kv][q], lane: q = lr, kv = n*16+lg*4+reg
        f32x4 sacc[4];
        #pragma unroll
        for (int n = 0; n < 4; ++n) {
            sacc[n] = __builtin_amdgcn_mfma_f32_16x16x32_bf16(kf[0][n], qf[0], z4, 0, 0, 0);
            sacc[n] = __builtin_amdgcn_mfma_f32_16x16x32_bf16(kf[1][n], qf[1], sacc[n], 0, 0, 0);
        }

        // mask (fast path when all 64 live)
        unsigned long long bb = __ballot(mv != 0);
        if (bb != ~0ULL) {
            #pragma unroll
            for (int n = 0; n < 4; ++n)
                #pragma unroll
                for (int reg = 0; reg < 4; ++reg) {
                    int kv = n * 16 + lg * 4 + reg;
                    if (!((bb >> kv) & 1)) sacc[n][reg] = -1e30f;
                }
        }

        // row max: balanced tree + 2 shfl
        float a0 = fmaxf(fmaxf(sacc[0][0], sacc[0][1]), fmaxf(sacc[0][2], sacc[0][3]));
        float a1 = fmaxf(fmaxf(sacc[1][0], sacc[1][1]), fmaxf(sacc[1][2], sacc[1][3]));
        float a2 = fmaxf(fmaxf(sacc[2][0], sacc[2][1]), fmaxf(sacc[2][2], sacc[2][3]));
        float a3 = fmaxf(fmaxf(sacc[3][0], sacc[3][1]), fmaxf(sacc[3][2], sacc[3][3]));
        float tmax = fmaxf(fmaxf(a0, a1), fmaxf(a2, a3));
        tmax = fmaxf(tmax, __shfl_xor(tmax, 16));
        tmax = fmaxf(tmax, __shfl_xor(tmax, 32));

        // defer-max rescale (T13, THR=8)
        if (__any(tmax > mrow + 8.f)) {
            float mnew = fmaxf(mrow, tmax);
            float sc = (mrow == -INFINITY) ? 0.f : __expf(mrow - mnew);
            lrow *= sc;
            mrow = mnew;
            #pragma unroll
            for (int reg = 0; reg < 4; ++reg) {
                float scq = __shfl(sc, lg * 4 + reg);
                #pragma unroll
                for (int n = 0; n < 4; ++n) oacc[n][reg] *= scq;
            }
        }

        // P = exp(S - m), row-sum, pack bf16, swizzled LDS store
        float ps = 0.f;
        #pragma unroll
        for (int n = 0; n < 4; ++n) {
            float p0 = __expf(sacc[n][0] - mrow);
            float p1 = __expf(sacc[n][1] - mrow);
            float p2 = __expf(sacc[n][2] - mrow);
            float p3 = __expf(sacc[n][3] - mrow);
            ps += (p0 + p1) + (p2 + p3);
            ushort4 wv;
            wv.x = bfc(p0); wv.y = bfc(p1); wv.z = bfc(p2); wv.w = bfc(p3);
            int gb = 2 * n + (lg >> 1);
            int col = ((gb ^ sw3) << 3) + (lg & 1) * 4;
            *(ushort4*)(prow + col) = wv;
        }
        ps += __shfl_xor(ps, 16);
        ps += __shfl_xor(ps, 32);
        lrow += ps;

        // V fragments (B-operand): col d = n*16+lr, k(kv) = kk*32+lg*8 (^swz)
        bf16x8 vf[2][4];
        #pragma unroll
        for (int kk = 0; kk < 2; ++kk)
            #pragma unroll
            for (int n = 0; n < 4; ++n)
                vf[kk][n] = *(const bf16x8*)(Vc + (n * 16 + lr) * 64 + ((kk * 32 + lg * 8) ^ swk));

        // P fragments (A-operand) from per-wave LDS bounce
        bf16x8 pf[2];
        #pragma unroll
        for (int kk2 = 0; kk2 < 2; ++kk2)
            pf[kk2] = *(const bf16x8*)(prow + (((kk2 * 4 + lg) ^ sw3) << 3));

        // O += P V
        #pragma unroll
        for (int kk2 = 0; kk2 < 2; ++kk2)
            #pragma unroll
            for (int n = 0; n < 4; ++n)
                oacc[n] = __builtin_amdgcn_mfma_f32_16x16x32_bf16(pf[kk2], vf[kk2][n], oacc[n], 0, 0, 0);
    }

    // epilogue: O rows q = lg*4+reg, cols d = n*16+lr
    #pragma unroll
    for (int reg = 0; reg < 4; ++reg) {
        float lq = __shfl(lrow, lg * 4 + reg);
        float linv = 1.0f / lq;
        int qrow = qrow0 + lg * 4 + reg;
        #pragma unroll
        for (int n = 0; n < 4; ++n)
            obuf[((size_t)b * 2048 + qrow) * 1024 + h * 64 + n * 16 + lr] = bfc(oacc[n][reg] * linv);
    }
}

extern "C" void kernel_launch(void* const* d_in, const int* in_sizes, int n_in,
                              void* d_out, int out_size, void* d_ws, size_t ws_size,
                              hipStream_t stream) {
    const float* x      = (const float*)d_in[0];
    const int* key_mask = (const int*)d_in[1];
    const float* w_qkv  = (const float*)d_in[2];
    const float* w_proj = (const float*)d_in[3];
    float* out = (float*)d_out;

    char* ws = (char*)d_ws;
    unsigned short* qb  = (unsigned short*)(ws);
    unsigned short* kb  = (unsigned short*)(ws + 8388608);
    unsigned short* vtb = (unsigned short*)(ws + 16777216);
    unsigned short* ob  = (unsigned short*)(ws + 25165824);
    unsigned short* wqT = (unsigned short*)(ws + 33554432);
    unsigned short* wpT = (unsigned short*)(ws + 39845888);
    float2*         tab = (float2*)(ws + 41943040);

    dim3 blk(256);
    prep_wT<<<dim3(96, 32), blk, 0, stream>>>(w_qkv, wqT, 3072);
    prep_wT<<<dim3(32, 32), blk, 0, stream>>>(w_proj, wpT, 1024);
    prep_rope<<<dim3(256), blk, 0, stream>>>(tab);
    gemm_kernel<0><<<dim3(24, 32), blk, 0, stream>>>(x, wqT, tab, qb, kb, vtb, nullptr, 3072);
    attn_kernel<<<dim3(512), dim3(512), 0, stream>>>(qb, kb, vtb, key_mask, ob);
    gemm_kernel<1><<<dim3(8, 32), blk, 0, stream>>>(ob, wpT, nullptr, nullptr, nullptr, nullptr, out, 1024);
}

// Round 8
// 173.809 us; speedup vs baseline: 1.3796x; 1.1120x over previous
//
#include <hip/hip_runtime.h>
#include <hip/hip_bf16.h>
#include <math.h>

// B=2, L=2048, D=1024, H=16, Dh=64. M = B*L = 4096.
// prep:    x -> bf16 SWIZZLED xsw; w_qkv/w_proj -> bf16 transposed SWIZZLED; rope table
// gemm<0>: xsw @ wqT + RoPE -> q*0.125 (natural), k (row-XOR), v^T (row-tile-XOR)
// attn:    flash attention (swapped QK^T, LDS dbuf K/V) -> ob bf16 SWIZZLED [B,L,D]
// gemm<1>: ob @ wpT -> f32 d_out
// Swizzle convention (T2): within each 64-elem K-chunk of a row, 8-elem block jj
// is stored at jj ^ (row & 7). LDS stays linear (global_load_lds); reads XOR back.

typedef __attribute__((ext_vector_type(8))) short bf16x8;
typedef __attribute__((ext_vector_type(4))) float f32x4;

__device__ __forceinline__ unsigned short f2bf(float f) {
    union { float f; unsigned int u; } v; v.f = f;
    unsigned int u = v.u;
    return (unsigned short)((u + 0x7FFFu + ((u >> 16) & 1u)) >> 16);
}

__device__ __forceinline__ unsigned short bfc(float f) {
    union { __hip_bfloat16 h; unsigned short u; } c;
    c.h = __float2bfloat16(f);
    return c.u;
}

__device__ __forceinline__ void gload_lds16(const unsigned short* g, unsigned short* l) {
    __builtin_amdgcn_global_load_lds(
        (const __attribute__((address_space(1))) void*)g,
        (__attribute__((address_space(3))) void*)l, 16, 0, 0);
}

// ---- prep: x f32 [4096][1024] -> bf16 swizzled ----
__global__ __launch_bounds__(256) void prep_xbf(const float* __restrict__ x,
                                                unsigned short* __restrict__ xsw)
{
    int i = blockIdx.x * 256 + threadIdx.x;        // 4096*128 8-elem blocks
    int row = i >> 7, blk = i & 127;
    int swblk = (blk & ~7) | ((blk ^ row) & 7);
    const float* src = x + ((size_t)row << 10) + (blk << 3);
    float4 f0 = *(const float4*)(src);
    float4 f1 = *(const float4*)(src + 4);
    ushort4 h0, h1;
    h0.x = f2bf(f0.x); h0.y = f2bf(f0.y); h0.z = f2bf(f0.z); h0.w = f2bf(f0.w);
    h1.x = f2bf(f1.x); h1.y = f2bf(f1.y); h1.z = f2bf(f1.z); h1.w = f2bf(f1.w);
    ushort4* dst = (ushort4*)(xsw + ((size_t)row << 10) + (swblk << 3));
    dst[0] = h0; dst[1] = h1;
}

// ---- prep: transpose f32 [1024][Ncols] -> bf16 [Ncols][1024], K-swizzled ----
__global__ __launch_bounds__(256) void prep_wT(const float* __restrict__ w,
                                               unsigned short* __restrict__ wT, int Ncols)
{
    __shared__ unsigned short t[32][34];
    int tid = threadIdx.x;
    int n0 = blockIdx.x * 32, k0 = blockIdx.y * 32;
    int r = tid >> 3, c4 = (tid & 7) * 4;
    float4 f = *(const float4*)(w + (size_t)(k0 + r) * Ncols + n0 + c4);
    t[c4 + 0][r] = f2bf(f.x);
    t[c4 + 1][r] = f2bf(f.y);
    t[c4 + 2][r] = f2bf(f.z);
    t[c4 + 3][r] = f2bf(f.w);
    __syncthreads();
    ushort4 o;
    o.x = t[r][c4]; o.y = t[r][c4 + 1]; o.z = t[r][c4 + 2]; o.w = t[r][c4 + 3];
    int n = n0 + r, k = k0 + c4;
    int ksw = (k & ~63) | ((((k >> 3) ^ n) & 7) << 3) | (k & 7);
    *(ushort4*)(wT + (size_t)n * 1024 + ksw) = o;
}

// ---- prep: rope table tab[pos][d] = (cos, sin), pos<2048, d<32 ----
__global__ __launch_bounds__(256) void prep_rope(float2* __restrict__ tab)
{
    int i = blockIdx.x * 256 + threadIdx.x;        // 65536
    int pos = i >> 5, d = i & 31;
    float inv = expf(-0.28782313662f * (float)d);  // 10000^(-d/32)
    float ang = (float)pos * inv;
    float s, c;
    sincosf(ang, &s, &c);
    tab[i] = make_float2(c, s);
}

// ---- main GEMM: 128x128 tile, BK=64, both operands bf16 swizzled via global_load_lds ----
// MODE 0: N=3072, epilogue RoPE scatter q/k/v^T.  MODE 1: N=1024, epilogue f32 C.
template<int MODE>
__global__ __launch_bounds__(256) void gemm_kernel(
    const unsigned short* __restrict__ Asw, const unsigned short* __restrict__ BT,
    const float2* __restrict__ ropetab,
    unsigned short* __restrict__ qb, unsigned short* __restrict__ kb,
    unsigned short* __restrict__ vb, float* __restrict__ Cout, int N)
{
    const int K = 1024;
    __shared__ __align__(16) unsigned short As[128 * 64];
    __shared__ __align__(16) unsigned short Bs[128 * 64];
    int tid = threadIdx.x;
    int wid = tid >> 6, lane = tid & 63, lr = lane & 15, lg = lane >> 4;
    int wm = (wid >> 1) * 64, wn = (wid & 1) * 64;

    // XCD-chunked 1D grid: each XCD owns 4 consecutive row-panels x all col-panels
    int NB = N >> 7;                 // col panels: 24 or 8
    int per = NB * 4;                // blocks per XCD: 96 or 32
    int flat = blockIdx.x;
    int w = (flat & 7) * per + (flat >> 3);
    int row0 = (w / NB) * 128, col0 = (w % NB) * 128;

    int swk = (lr & 7) << 3;         // LDS read de-swizzle (elements)

    f32x4 acc[4][4];
    #pragma unroll
    for (int m = 0; m < 4; ++m)
        #pragma unroll
        for (int n = 0; n < 4; ++n)
            #pragma unroll
            for (int i = 0; i < 4; ++i) acc[m][n][i] = 0.0f;

    for (int k0 = 0; k0 < K; k0 += 64) {
        #pragma unroll
        for (int i = 0; i < 4; ++i) {
            int cbase = (i * 4 + wid) * 64;
            int c = cbase + lane;
            int r = c >> 3, cc = (c & 7) * 8;
            gload_lds16(BT + (size_t)(col0 + r) * K + k0 + cc, Bs + cbase * 8);
            gload_lds16(Asw + (size_t)(row0 + r) * K + k0 + cc, As + cbase * 8);
        }
        __syncthreads();
        #pragma unroll
        for (int kk = 0; kk < 2; ++kk) {
            bf16x8 af[4], bfr[4];
            #pragma unroll
            for (int m = 0; m < 4; ++m)
                af[m] = *(const bf16x8*)(&As[(wm + m * 16 + lr) * 64 + ((kk * 32 + lg * 8) ^ swk)]);
            #pragma unroll
            for (int n = 0; n < 4; ++n)
                bfr[n] = *(const bf16x8*)(&Bs[(wn + n * 16 + lr) * 64 + ((kk * 32 + lg * 8) ^ swk)]);
            #pragma unroll
            for (int m = 0; m < 4; ++m)
                #pragma unroll
                for (int n = 0; n < 4; ++n)
                    acc[m][n] = __builtin_amdgcn_mfma_f32_16x16x32_bf16(af[m], bfr[n], acc[m][n], 0, 0, 0);
        }
        __syncthreads();
    }

    if (MODE == 1) {
        #pragma unroll
        for (int m = 0; m < 4; ++m)
            #pragma unroll
            for (int reg = 0; reg < 4; ++reg) {
                int grow = row0 + wm + m * 16 + lg * 4 + reg;
                #pragma unroll
                for (int n = 0; n < 4; ++n)
                    Cout[(size_t)grow * N + col0 + wn + n * 16 + lr] = acc[m][n][reg];
            }
    } else {
        #pragma unroll
        for (int m = 0; m < 4; ++m)
            #pragma unroll
            for (int reg = 0; reg < 4; ++reg) {
                int grow = row0 + wm + m * 16 + lg * 4 + reg;
                int pos = grow & 2047;
                int bb = grow >> 11;
                #pragma unroll
                for (int n = 0; n < 4; ++n) {
                    int col = col0 + wn + n * 16 + lr;
                    int part = col >> 10;           // 0=q 1=k 2=v
                    int h = (col >> 6) & 15;
                    int d = col & 63;
                    float v0 = acc[m][n][reg];
                    if (part == 2) {
                        // v^T with XOR-swizzled 64-wide row tiles: elem (d, pos)
                        int posl = (pos & 63) ^ ((d & 7) << 3);
                        vb[((size_t)bb * 16 + h) * 131072 + (size_t)d * 2048 + (pos & ~63) + posl] = f2bf(v0);
                    } else if (n < 2) {             // d<32, partner at n+2 (d+32) same lane
                        float v1 = acc[m][n + 2][reg];
                        float2 cs = ropetab[pos * 32 + d];
                        size_t base = (((size_t)bb * 16 + h) * 2048 + pos) * 64;
                        float e0 = v0 * cs.x - v1 * cs.y;
                        float e1 = v1 * cs.x + v0 * cs.y;
                        if (part == 0) {            // q natural, fold softmax scale
                            qb[base + d]      = f2bf(e0 * 0.125f);
                            qb[base + d + 32] = f2bf(e1 * 0.125f);
                        } else {                    // k row-swizzled
                            int sw = (pos & 7) << 3;
                            kb[base + (d ^ sw)]        = f2bf(e0);
                            kb[base + ((d + 32) ^ sw)] = f2bf(e1);
                        }
                    }
                }
            }
    }
}

// ---- flash attention: 8 waves x 16 q-rows; dbuf LDS K/V via global_load_lds ----
#define PST 68   // Ps row stride (ushorts)
__global__ __launch_bounds__(512, 4) void attn_kernel(
    const unsigned short* __restrict__ qbuf, const unsigned short* __restrict__ kbuf,
    const unsigned short* __restrict__ vtbuf, const int* __restrict__ mask,
    unsigned short* __restrict__ obuf)
{
    __shared__ __align__(16) unsigned short Ks[2][4096];   // [kvl][d^swz] 64x64
    __shared__ __align__(16) unsigned short Vs[2][4096];   // [d][kvl^swz] 64x64
    __shared__ __align__(16) unsigned short Ps[8][16][PST];

    // XCD-chunked remap: 512 blocks, 8 XCDs, 64 consecutive w per XCD (4 bh -> 2MB K/V in L2)
    int flat = blockIdx.x;
    int w = ((flat & 7) << 6) + (flat >> 3);
    int bh = w >> 4, qt = w & 15;
    int b = bh >> 4, h = bh & 15;
    int tid = threadIdx.x, wid = tid >> 6, lane = tid & 63, lr = lane & 15, lg = lane >> 4;
    int qrow0 = qt * 128 + wid * 16;
    const size_t bhbase = (size_t)bh * (2048 * 64);
    const unsigned short* kB = kbuf + bhbase;
    const unsigned short* vt = vtbuf + bhbase;   // [64][2048] swizzled row-tiles
    const int* mptr = mask + b * 2048;
    unsigned short* prow = &Ps[wid][lr][0];
    int sw3 = lr & 3;
    int swk = (lr & 7) << 3;                      // K/V LDS read swizzle (elements)

    // Q fragments (B-operand): col q = lr, k = kk*32+lg*8
    bf16x8 qf[2];
    #pragma unroll
    for (int kk = 0; kk < 2; ++kk)
        qf[kk] = *(const bf16x8*)(qbuf + bhbase + (size_t)(qrow0 + lr) * 64 + kk * 32 + lg * 8);

    f32x4 oacc[4];
    #pragma unroll
    for (int n = 0; n < 4; ++n)
        #pragma unroll
        for (int i = 0; i < 4; ++i) oacc[n][i] = 0.0f;
    float mrow = -INFINITY, lrow = 0.f;
    const f32x4 z4 = {0.f, 0.f, 0.f, 0.f};

    // staging: per thread 1x16B of K + 1x16B of V
    auto stage = [&](int t, int buf) {
        gload_lds16(kB + (size_t)t * 4096 + tid * 8, &Ks[buf][wid * 512]);
        gload_lds16(vt + (size_t)(tid >> 3) * 2048 + t * 64 + (tid & 7) * 8, &Vs[buf][wid * 512]);
    };

    stage(0, 0);
    #pragma unroll 1
    for (int t = 0; t < 32; ++t) {
        int cur = t & 1;
        __syncthreads();                  // drains staging of buf[cur]
        if (t < 31) stage(t + 1, cur ^ 1);
        const unsigned short* Kc = Ks[cur];
        const unsigned short* Vc = Vs[cur];
        int mv = mptr[t * 64 + lane];

        // K fragments (A-operand): row kv = n*16+lr, k(d) = kk*32+lg*8 (^swz)
        bf16x8 kf[2][4];
        #pragma unroll
        for (int kk = 0; kk < 2; ++kk)
            #pragma unroll
            for (int n = 0; n < 4; ++n)
                kf[kk][n] = *(const bf16x8*)(Kc + (n * 16 + lr) * 64 + ((kk * 32 + lg * 8) ^ swk));

        // S^T = K Q^T : D[kv][q], lane: q = lr, kv = n*16+lg*4+reg
        f32x4 sacc[4];
        #pragma unroll
        for (int n = 0; n < 4; ++n) {
            sacc[n] = __builtin_amdgcn_mfma_f32_16x16x32_bf16(kf[0][n], qf[0], z4, 0, 0, 0);
            sacc[n] = __builtin_amdgcn_mfma_f32_16x16x32_bf16(kf[1][n], qf[1], sacc[n], 0, 0, 0);
        }

        // mask (fast path when all 64 live)
        unsigned long long bb = __ballot(mv != 0);
        if (bb != ~0ULL) {
            #pragma unroll
            for (int n = 0; n < 4; ++n)
                #pragma unroll
                for (int reg = 0; reg < 4; ++reg) {
                    int kv = n * 16 + lg * 4 + reg;
                    if (!((bb >> kv) & 1)) sacc[n][reg] = -1e30f;
                }
        }

        // row max: balanced tree + 2 shfl
        float a0 = fmaxf(fmaxf(sacc[0][0], sacc[0][1]), fmaxf(sacc[0][2], sacc[0][3]));
        float a1 = fmaxf(fmaxf(sacc[1][0], sacc[1][1]), fmaxf(sacc[1][2], sacc[1][3]));
        float a2 = fmaxf(fmaxf(sacc[2][0], sacc[2][1]), fmaxf(sacc[2][2], sacc[2][3]));
        float a3 = fmaxf(fmaxf(sacc[3][0], sacc[3][1]), fmaxf(sacc[3][2], sacc[3][3]));
        float tmax = fmaxf(fmaxf(a0, a1), fmaxf(a2, a3));
        tmax = fmaxf(tmax, __shfl_xor(tmax, 16));
        tmax = fmaxf(tmax, __shfl_xor(tmax, 32));

        // defer-max rescale (T13, THR=8)
        if (__any(tmax > mrow + 8.f)) {
            float mnew = fmaxf(mrow, tmax);
            float sc = (mrow == -INFINITY) ? 0.f : __expf(mrow - mnew);
            lrow *= sc;
            mrow = mnew;
            #pragma unroll
            for (int reg = 0; reg < 4; ++reg) {
                float scq = __shfl(sc, lg * 4 + reg);
                #pragma unroll
                for (int n = 0; n < 4; ++n) oacc[n][reg] *= scq;
            }
        }

        // P = exp(S - m), row-sum, pack bf16, swizzled LDS store
        float ps = 0.f;
        #pragma unroll
        for (int n = 0; n < 4; ++n) {
            float p0 = __expf(sacc[n][0] - mrow);
            float p1 = __expf(sacc[n][1] - mrow);
            float p2 = __expf(sacc[n][2] - mrow);
            float p3 = __expf(sacc[n][3] - mrow);
            ps += (p0 + p1) + (p2 + p3);
            ushort4 wv;
            wv.x = bfc(p0); wv.y = bfc(p1); wv.z = bfc(p2); wv.w = bfc(p3);
            int gb = 2 * n + (lg >> 1);
            int col = ((gb ^ sw3) << 3) + (lg & 1) * 4;
            *(ushort4*)(prow + col) = wv;
        }
        ps += __shfl_xor(ps, 16);
        ps += __shfl_xor(ps, 32);
        lrow += ps;

        // V fragments (B-operand): col d = n*16+lr, k(kv) = kk*32+lg*8 (^swz)
        bf16x8 vf[2][4];
        #pragma unroll
        for (int kk = 0; kk < 2; ++kk)
            #pragma unroll
            for (int n = 0; n < 4; ++n)
                vf[kk][n] = *(const bf16x8*)(Vc + (n * 16 + lr) * 64 + ((kk * 32 + lg * 8) ^ swk));

        // P fragments (A-operand) from per-wave LDS bounce
        bf16x8 pf[2];
        #pragma unroll
        for (int kk2 = 0; kk2 < 2; ++kk2)
            pf[kk2] = *(const bf16x8*)(prow + (((kk2 * 4 + lg) ^ sw3) << 3));

        // O += P V
        #pragma unroll
        for (int kk2 = 0; kk2 < 2; ++kk2)
            #pragma unroll
            for (int n = 0; n < 4; ++n)
                oacc[n] = __builtin_amdgcn_mfma_f32_16x16x32_bf16(pf[kk2], vf[kk2][n], oacc[n], 0, 0, 0);
    }

    // epilogue: O rows q = lg*4+reg, cols d = n*16+lr; ob written PRE-SWIZZLED for gemm1
    #pragma unroll
    for (int reg = 0; reg < 4; ++reg) {
        float lq = __shfl(lrow, lg * 4 + reg);
        float linv = 1.0f / lq;
        int qrow = qrow0 + lg * 4 + reg;
        int qsw = qrow & 7;
        #pragma unroll
        for (int n = 0; n < 4; ++n) {
            int jj = n * 2 + (lr >> 3);
            int colsw = h * 64 + (((jj ^ qsw) & 7) << 3) + (lr & 7);
            obuf[((size_t)b * 2048 + qrow) * 1024 + colsw] = bfc(oacc[n][reg] * linv);
        }
    }
}

extern "C" void kernel_launch(void* const* d_in, const int* in_sizes, int n_in,
                              void* d_out, int out_size, void* d_ws, size_t ws_size,
                              hipStream_t stream) {
    const float* x      = (const float*)d_in[0];
    const int* key_mask = (const int*)d_in[1];
    const float* w_qkv  = (const float*)d_in[2];
    const float* w_proj = (const float*)d_in[3];
    float* out = (float*)d_out;

    char* ws = (char*)d_ws;
    unsigned short* qb  = (unsigned short*)(ws);
    unsigned short* kb  = (unsigned short*)(ws + 8388608);
    unsigned short* vtb = (unsigned short*)(ws + 16777216);
    unsigned short* xob = (unsigned short*)(ws + 25165824);  // xsw for gemm0, then ob for gemm1
    unsigned short* wqT = (unsigned short*)(ws + 33554432);
    unsigned short* wpT = (unsigned short*)(ws + 39845888);
    float2*         tab = (float2*)(ws + 41943040);

    dim3 blk(256);
    prep_xbf<<<dim3(2048), blk, 0, stream>>>(x, xob);
    prep_wT<<<dim3(96, 32), blk, 0, stream>>>(w_qkv, wqT, 3072);
    prep_wT<<<dim3(32, 32), blk, 0, stream>>>(w_proj, wpT, 1024);
    prep_rope<<<dim3(256), blk, 0, stream>>>(tab);
    gemm_kernel<0><<<dim3(768), blk, 0, stream>>>(xob, wqT, tab, qb, kb, vtb, nullptr, 3072);
    attn_kernel<<<dim3(512), dim3(512), 0, stream>>>(qb, kb, vtb, key_mask, xob);
    gemm_kernel<1><<<dim3(256), blk, 0, stream>>>(xob, wpT, nullptr, nullptr, nullptr, nullptr, out, 1024);
}